// Round 7
// baseline (820.786 us; speedup 1.0000x reference)
//
#include <hip/hip_runtime.h>
#include <math.h>

// CapsuleLayer dynamic routing, MI355X fp32. Round 9: B_CHUNK 8->16 (latency).
// B=64, In=2048, Din=16, Nc=32, Dc=32, ROUTINGS=3.
// Identity: b starts at 0 => logits_t = hat . (v1+..+v_{t-1}); never store b or hat.
//
// Round-8 post-mortem: scalar-x neutral (148us both ways) -> W-load LATENCY is
// the bottleneck: ~390 cy exposed stall per k-quarter (4 loads vs only 128 FMA
// instrs of cover; all waves stall in lockstep). Fix: B_CHUNK 16 -> 256 FMA
// instrs per quarter (2x latency cover), half the total W traffic (512 blocks).
// Regs: ph0 ~106 (16 waves/CU band), ph1 ~186 (256-cap via (256,2), 2 blk/CU =
// grid exactly resident). WRITE_SIZE is the spill canary (~33-40MB = clean).
// Kept: transposed Wt (lane-contiguous loads), k-quarter ping-pong, scalar x,
// XCD-clustered swizzle, lgkm-only barriers in ph1, private-P + wide reduce.

#define B_TOT   64
#define IN_CAPS 2048
#define DIN     16
#define NC      32
#define DC      32
#define JD      (NC * DC)            // 1024
#define B_CHUNK 16
#define I_CHUNK 16
#define N_IG    (IN_CAPS / I_CHUNK)  // 128
#define N_BG    (B_TOT / B_CHUNK)    // 4
#define EPS_SQ  1e-7f

#define WT_CHUNKS ((size_t)IN_CAPS * 4096)   // 8.4M float4 = 128 MB

// Raw workgroup barrier: drain LDS ops only (no vmcnt) -> W prefetch survives.
#define LDS_BARRIER() do {                                  \
    asm volatile("" ::: "memory");                          \
    asm volatile("s_waitcnt lgkmcnt(0)");                   \
    __builtin_amdgcn_s_barrier();                           \
    __builtin_amdgcn_sched_barrier(0);                      \
} while (0)

// ---- W transpose: Wt chunk i*4096 + (k4*4+r)*256 + (j*8+dq)
//      = W[j][i][dq*4+r][k4*4..k4*4+3]
// One block per i. Coalesced read (1KB/wave-instr) -> LDS (swizzled) ->
// coalesced write (1KB/wave-instr). sigma(c) = c ^ ((c>>4)&7): conflict-free
// on both store (low3 ^= (t>>4)&7) and gather ((c>>4)&7 == dq) phases.
__global__ __launch_bounds__(256) void transpose_W(const float* __restrict__ W,
                                                   float* __restrict__ Wt)
{
    __shared__ float4 tile[4096];            // 64 KB
    const int i = blockIdx.x;
    const int t = threadIdx.x;
    const float4* Wf = (const float4*)W;
    float4 v[16];
#pragma unroll
    for (int q = 0; q < 16; ++q) {
        const int c  = t + 256 * q;
        const int jj = c >> 7, off = c & 127;
        v[q] = Wf[((size_t)jj * IN_CAPS + i) * 128 + off];
    }
#pragma unroll
    for (int q = 0; q < 16; ++q) {
        const int c = t + 256 * q;
        tile[c ^ ((c >> 4) & 7)] = v[q];
    }
    __syncthreads();
    float4* Wo = (float4*)Wt + (size_t)i * 4096;
    const int j = t >> 3, dq = t & 7;
#pragma unroll
    for (int k4 = 0; k4 < 4; ++k4)
#pragma unroll
        for (int r = 0; r < 4; ++r) {
            const int cg = j * 128 + dq * 16 + r * 4 + k4;
            Wo[(k4 * 4 + r) * 256 + t] = tile[cg ^ dq];   // (cg>>4)&7 == dq
        }
}

// Load one k-quarter (all 4 d-rows at one k4).
// TRANS=1: base = Wt + i0*4096 + t chunks (lane-contiguous).
// TRANS=0: base = W + (j*IN_CAPS + i0)*128 + doff*4 chunks (original layout).
template <int TRANS>
__device__ __forceinline__ void wload(float4 (&w)[4], const float4* __restrict__ base,
                                      int il, int k4) {
    if (TRANS) {
        const float4* p = base + (size_t)il * 4096 + k4 * 1024;
        w[0] = p[0];
        w[1] = p[256];
        w[2] = p[512];
        w[3] = p[768];
    } else {
        const float4* p = base + (size_t)il * 128 + k4;
        w[0] = p[0];
        w[1] = p[4];
        w[2] = p[8];
        w[3] = p[12];
    }
}

// One k-quarter of compute. x read via WAVE-UNIFORM address -> scalar loads;
// each v_fma gets one SGPR operand (x component) + VGPR w + VGPR acc.
// 16 b x 4 r = 256 FMA instrs per quarter (the latency cover).
template <bool ACCUM>
__device__ __forceinline__ void qcomp(const float4 (&w)[4],
                                      const float* __restrict__ xi,
                                      int k4, float (*__restrict__ dst)[4])
{
#pragma unroll
    for (int b = 0; b < B_CHUNK; ++b) {
        const float* xb = xi + (size_t)b * (IN_CAPS * DIN) + k4 * 4;
        const float x0 = xb[0], x1 = xb[1], x2 = xb[2], x3 = xb[3];
#pragma unroll
        for (int r = 0; r < 4; ++r) {
            const float s = w[r].x * x0 + w[r].y * x1 + w[r].z * x2 + w[r].w * x3;
            if (ACCUM) dst[b][r] += s;
            else       dst[b][r] = s;
        }
    }
}

// PHASE 0: c = 1/32 uniform (softmax of zeros), plain sum.
// PHASE 1: logits = hat . vsum, softmax over j, weighted sum.
template <int PHASE, int ATOMIC, int TRANS>
__launch_bounds__(256, 2)
__global__ void caps_pass(const float* __restrict__ x,
                          const float* __restrict__ Wp,   // W (TRANS=0) or Wt (TRANS=1)
                          const float* __restrict__ vsum,
                          float* __restrict__ P)
{
    __shared__ float c_s[PHASE ? 2 : 1][B_CHUNK][NC];       // 4 KB (phase 1)

    const int t    = threadIdx.x;           // 256 threads
    const int j    = t >> 3;                // 0..31 output capsule
    const int dq   = t & 7;                 // d-quad 0..7
    const int doff = dq * 4;
    const int jd0  = j * DC + doff;

    // XCD-clustered swizzle (round-robin XCD = linear_id % 8):
    // all 4 bg-siblings of one ig occupy consecutive slots on ONE XCD.
    const int r   = blockIdx.x;             // 0..511
    const int xcd = r & 7;
    const int s   = r >> 3;                 // 0..63
    const int bg  = s & 3;
    const int ig  = (s >> 2) * 8 + xcd;     // 0..127
    const int b0  = bg * B_CHUNK;
    const int i0  = ig * I_CHUNK;

    // W base for this thread
    const float4* base = TRANS
        ? (const float4*)Wp + (size_t)i0 * 4096 + t
        : (const float4*)Wp + ((size_t)j * IN_CAPS + i0) * 128 + doff * 4;

    float4 wE[4], wO[4];
    wload<TRANS>(wE, base, 0, 0);           // prologue: quarter (il=0, k4=0)

    float acc[B_CHUNK][4];
#pragma unroll
    for (int b = 0; b < B_CHUNK; ++b)
#pragma unroll
        for (int dd = 0; dd < 4; ++dd) acc[b][dd] = 0.f;

    float h[B_CHUNK][4];   // phase-1 hat fragments (registers); dead in phase 0
    int buf = 0;

#pragma unroll 1
    for (int il = 0; il < I_CHUNK; ++il) {
        // wave-uniform x row base for this il (scalar loads inside qcomp)
        const float* xi = x + ((size_t)b0 * IN_CAPS + (i0 + il)) * DIN;
        float (*dst)[4] = PHASE ? h : acc;

        // 4 k-quarters, wE/wO ping-pong; next quarter's load issued before the
        // current quarter's compute.
        wload<TRANS>(wO, base, il, 1);
        if (PHASE == 0) qcomp<true >(wE, xi, 0, acc);
        else            qcomp<false>(wE, xi, 0, h);
        wload<TRANS>(wE, base, il, 2);
        qcomp<true>(wO, xi, 1, dst);
        wload<TRANS>(wO, base, il, 3);
        qcomp<true>(wE, xi, 2, dst);
        if (il + 1 < I_CHUNK) wload<TRANS>(wE, base, il + 1, 0);
        qcomp<true>(wO, xi, 3, dst);

        if (PHASE == 1) {
            // logits: lp[b] = hat[b] . vsum[b] over this thread's 4 d's (vsum
            // from global: coalesced, L2-resident), then reduce over the 8
            // dq-threads sharing j.
            float lp[B_CHUNK];
#pragma unroll
            for (int b = 0; b < B_CHUNK; ++b) {
                const float4 vv =
                    *(const float4*)&vsum[(size_t)(b0 + b) * JD + jd0];
                lp[b] = h[b][0]*vv.x + h[b][1]*vv.y + h[b][2]*vv.z + h[b][3]*vv.w;
                lp[b] += __shfl_xor(lp[b], 1, 8);
                lp[b] += __shfl_xor(lp[b], 2, 8);
                lp[b] += __shfl_xor(lp[b], 4, 8);
            }
            if (dq == 0) {
#pragma unroll
                for (int b = 0; b < B_CHUNK; ++b) c_s[buf][b][j] = lp[b];
            }
            LDS_BARRIER();

            // softmax over j: 256 threads cover 16 b x 32 j -> each thread
            // handles rows tb and tb+8; width-32 butterflies per row.
            {
                const int tb = t >> 5, tj = t & 31;
                float l0 = c_s[buf][tb][tj];
                float l1 = c_s[buf][tb + 8][tj];
                float m0 = l0, m1 = l1;
#pragma unroll
                for (int off = 1; off < 32; off <<= 1) {
                    m0 = fmaxf(m0, __shfl_xor(m0, off, 32));
                    m1 = fmaxf(m1, __shfl_xor(m1, off, 32));
                }
                const float e0 = __expf(l0 - m0);
                const float e1 = __expf(l1 - m1);
                float s0 = e0, s1 = e1;
#pragma unroll
                for (int off = 1; off < 32; off <<= 1) {
                    s0 += __shfl_xor(s0, off, 32);
                    s1 += __shfl_xor(s1, off, 32);
                }
                c_s[buf][tb][tj]     = e0 / s0;
                c_s[buf][tb + 8][tj] = e1 / s1;
            }
            LDS_BARRIER();

            // weighted accumulate from register-held hat
#pragma unroll
            for (int b = 0; b < B_CHUNK; ++b) {
                const float c = c_s[buf][b][j];    // broadcast read
                acc[b][0] += c * h[b][0];
                acc[b][1] += c * h[b][1];
                acc[b][2] += c * h[b][2];
                acc[b][3] += c * h[b][3];
            }
            buf ^= 1;   // next il writes the other c_s buffer: no WAR barrier needed
        }
    }

    const float scale = (PHASE == 0) ? (1.f / NC) : 1.f;
    if (ATOMIC) {
#pragma unroll
        for (int b = 0; b < B_CHUNK; ++b) {
            float* dstp = &P[(size_t)(b0 + b) * JD + jd0];
            atomicAdd(dstp + 0, acc[b][0] * scale);
            atomicAdd(dstp + 1, acc[b][1] * scale);
            atomicAdd(dstp + 2, acc[b][2] * scale);
            atomicAdd(dstp + 3, acc[b][3] * scale);
        }
    } else {
        // private partial: P[ig][b_global][jd], coalesced float4 stores
        float* dstp = P + ((size_t)ig * B_TOT + b0) * JD + jd0;
#pragma unroll
        for (int b = 0; b < B_CHUNK; ++b) {
            *(float4*)(dstp + (size_t)b * JD) =
                make_float4(acc[b][0] * scale, acc[b][1] * scale,
                            acc[b][2] * scale, acc[b][3] * scale);
        }
    }
}

// Sum nparts partials, squash over Dc=32, write per mode.
// Grid 256 blocks x 256 thr: block owns 64 float4-idx; thread sums an ig-slice
// (ig = slice, slice+4, ...), LDS-combine 4 slices, wave 0 squashes + stores.
// mode 0: VSUM = v ; 1: VSUM += v ; 2: OUT = v
__global__ __launch_bounds__(256) void reduce_squash(
    const float* __restrict__ Pf, int nparts,
    float* __restrict__ VSUMf, float* __restrict__ OUTf, int mode)
{
    __shared__ float4 sl[4][64];             // 4 KB
    const float4* P4 = (const float4*)Pf;
    const int t = threadIdx.x, i64 = t & 63, slice = t >> 6;
    const int idx = blockIdx.x * 64 + i64;   // 0..16383
    float4 v = make_float4(0.f, 0.f, 0.f, 0.f);
    for (int ig = slice; ig < nparts; ig += 4) {
        const float4 p = P4[(size_t)ig * (B_TOT * JD / 4) + idx];
        v.x += p.x; v.y += p.y; v.z += p.z; v.w += p.w;
    }
    sl[slice][i64] = v;
    __syncthreads();
    if (t < 64) {
        const float4 a = sl[0][t], b = sl[1][t], c = sl[2][t], d = sl[3][t];
        v.x = a.x + b.x + c.x + d.x;
        v.y = a.y + b.y + c.y + d.y;
        v.z = a.z + b.z + c.z + d.z;
        v.w = a.w + b.w + c.w + d.w;
        float s2 = v.x*v.x + v.y*v.y + v.z*v.z + v.w*v.w;
        s2 += __shfl_xor(s2, 1, 8);
        s2 += __shfl_xor(s2, 2, 8);
        s2 += __shfl_xor(s2, 4, 8);
        const float sc = s2 / (1.f + s2) * rsqrtf(s2 + EPS_SQ);
        const int gidx = blockIdx.x * 64 + t;
        float4 o = make_float4(v.x * sc, v.y * sc, v.z * sc, v.w * sc);
        float4* VSUM = (float4*)VSUMf;
        float4* OUT  = (float4*)OUTf;
        if (mode == 0) {
            VSUM[gidx] = o;
        } else if (mode == 1) {
            float4 u = VSUM[gidx];
            u.x += o.x; u.y += o.y; u.z += o.z; u.w += o.w;
            VSUM[gidx] = u;
        } else {
            OUT[gidx] = o;
        }
    }
}

extern "C" void kernel_launch(void* const* d_in, const int* in_sizes, int n_in,
                              void* d_out, int out_size, void* d_ws, size_t ws_size,
                              hipStream_t stream)
{
    const float* x = (const float*)d_in[0];   // [64, 2048, 16]
    const float* W = (const float*)d_in[1];   // [32, 2048, 32, 16]
    float* out = (float*)d_out;               // [64, 32, 32]

    const dim3 grid(N_IG * N_BG);             // 512 blocks (XCD-swizzled in-kernel)
    const dim3 blk(256);
    const dim3 rgrid(B_TOT * JD / 4 / 64);    // 256 blocks

    const size_t P_elems  = (size_t)N_IG * B_TOT * JD;              // 33.6 MB
    const size_t vs_elems = (size_t)B_TOT * JD;                     // 256 KB
    const size_t need_p   = (P_elems + vs_elems) * sizeof(float);
    const size_t need_t   = (WT_CHUNKS * 4 + P_elems + vs_elems) * sizeof(float);

    if (ws_size >= need_t) {
        // transposed-W path: lane-contiguous W loads (8 lines/wave-instr)
        float* Wt   = (float*)d_ws;
        float* P    = Wt + WT_CHUNKS * 4;
        float* VSUM = P + P_elems;
        transpose_W<<<dim3(IN_CAPS), blk, 0, stream>>>(W, Wt);
        caps_pass<0, 0, 1><<<grid, blk, 0, stream>>>(x, Wt, nullptr, P);
        reduce_squash<<<rgrid, blk, 0, stream>>>(P, N_IG, VSUM, out, 0);
        caps_pass<1, 0, 1><<<grid, blk, 0, stream>>>(x, Wt, VSUM, P);
        reduce_squash<<<rgrid, blk, 0, stream>>>(P, N_IG, VSUM, out, 1);
        caps_pass<1, 0, 1><<<grid, blk, 0, stream>>>(x, Wt, VSUM, P);
        reduce_squash<<<rgrid, blk, 0, stream>>>(P, N_IG, VSUM, out, 2);
    } else if (ws_size >= need_p) {
        // original-W path
        float* P    = (float*)d_ws;
        float* VSUM = P + P_elems;
        caps_pass<0, 0, 0><<<grid, blk, 0, stream>>>(x, W, nullptr, P);
        reduce_squash<<<rgrid, blk, 0, stream>>>(P, N_IG, VSUM, out, 0);
        caps_pass<1, 0, 0><<<grid, blk, 0, stream>>>(x, W, VSUM, P);
        reduce_squash<<<rgrid, blk, 0, stream>>>(P, N_IG, VSUM, out, 1);
        caps_pass<1, 0, 0><<<grid, blk, 0, stream>>>(x, W, VSUM, P);
        reduce_squash<<<rgrid, blk, 0, stream>>>(P, N_IG, VSUM, out, 2);
    } else {
        // atomic fallback
        float* S    = (float*)d_ws;
        float* VSUM = S + vs_elems;
        const size_t sbytes = vs_elems * sizeof(float);
        hipMemsetAsync(S, 0, sbytes, stream);
        caps_pass<0, 1, 0><<<grid, blk, 0, stream>>>(x, W, nullptr, S);
        reduce_squash<<<rgrid, blk, 0, stream>>>(S, 1, VSUM, out, 0);
        hipMemsetAsync(S, 0, sbytes, stream);
        caps_pass<1, 1, 0><<<grid, blk, 0, stream>>>(x, W, VSUM, S);
        reduce_squash<<<rgrid, blk, 0, stream>>>(S, 1, VSUM, out, 1);
        hipMemsetAsync(S, 0, sbytes, stream);
        caps_pass<1, 1, 0><<<grid, blk, 0, stream>>>(x, W, VSUM, S);
        reduce_squash<<<rgrid, blk, 0, stream>>>(S, 1, VSUM, out, 2);
    }
}

// Round 8
// 597.013 us; speedup vs baseline: 1.3748x; 1.3748x over previous
//
#include <hip/hip_runtime.h>
#include <math.h>

// CapsuleLayer dynamic routing, MI355X fp32. Round 10: TLP (B_CHUNK 4, 2048 blk).
// B=64, In=2048, Din=16, Nc=32, Dc=32, ROUTINGS=3.
// Identity: b starts at 0 => logits_t = hat . (v1+..+v_{t-1}); never store b or hat.
//
// Round-9 post-mortem: B_CHUNK=16 (more ILP) regressed 148->205us: allocator
// juggled 100+ live regs under a VGPR=80 allocation (AGPR/remat moves, VALU
// busy-time up, same FMA work). Round 8 base restored. Its profile: ~95% stall
// per wave, occupancy ~20% in every config tried -> exposed latency, too few
// waves. This round: the untested axis, more TLP at LOWER reg pressure:
//  - B_CHUNK 8->4, grid 1024->2048 (b-split; disjoint P rows => P size
//    unchanged, softmax per block intact: 4 b x all 32 j).
//  - Phase-0 regs ~65, phase-1 ~85-90 -> 20-28 resident waves/CU (was 8-16).
//  - Everything else = round 8: transposed Wt, depth-1 k-quarter ping-pong,
//    scalar x, XCD swizzle, lgkm-only barriers, private-P + wide reduce.

#define B_TOT   64
#define IN_CAPS 2048
#define DIN     16
#define NC      32
#define DC      32
#define JD      (NC * DC)            // 1024
#define B_CHUNK 4
#define I_CHUNK 16
#define N_IG    (IN_CAPS / I_CHUNK)  // 128
#define N_BG    (B_TOT / B_CHUNK)    // 16
#define EPS_SQ  1e-7f

#define WT_CHUNKS ((size_t)IN_CAPS * 4096)   // 8.4M float4 = 128 MB

// Raw workgroup barrier: drain LDS ops only (no vmcnt) -> W prefetch survives.
#define LDS_BARRIER() do {                                  \
    asm volatile("" ::: "memory");                          \
    asm volatile("s_waitcnt lgkmcnt(0)");                   \
    __builtin_amdgcn_s_barrier();                           \
    __builtin_amdgcn_sched_barrier(0);                      \
} while (0)

// ---- W transpose: Wt chunk i*4096 + (k4*4+r)*256 + (j*8+dq)
//      = W[j][i][dq*4+r][k4*4..k4*4+3]
// One block per i. Coalesced read (1KB/wave-instr) -> LDS (swizzled) ->
// coalesced write (1KB/wave-instr). sigma(c) = c ^ ((c>>4)&7): conflict-free
// on both store (low3 ^= (t>>4)&7) and gather ((c>>4)&7 == dq) phases.
__global__ __launch_bounds__(256) void transpose_W(const float* __restrict__ W,
                                                   float* __restrict__ Wt)
{
    __shared__ float4 tile[4096];            // 64 KB
    const int i = blockIdx.x;
    const int t = threadIdx.x;
    const float4* Wf = (const float4*)W;
    float4 v[16];
#pragma unroll
    for (int q = 0; q < 16; ++q) {
        const int c  = t + 256 * q;
        const int jj = c >> 7, off = c & 127;
        v[q] = Wf[((size_t)jj * IN_CAPS + i) * 128 + off];
    }
#pragma unroll
    for (int q = 0; q < 16; ++q) {
        const int c = t + 256 * q;
        tile[c ^ ((c >> 4) & 7)] = v[q];
    }
    __syncthreads();
    float4* Wo = (float4*)Wt + (size_t)i * 4096;
    const int j = t >> 3, dq = t & 7;
#pragma unroll
    for (int k4 = 0; k4 < 4; ++k4)
#pragma unroll
        for (int r = 0; r < 4; ++r) {
            const int cg = j * 128 + dq * 16 + r * 4 + k4;
            Wo[(k4 * 4 + r) * 256 + t] = tile[cg ^ dq];   // (cg>>4)&7 == dq
        }
}

// Load one k-quarter (all 4 d-rows at one k4).
// TRANS=1: base = Wt + i0*4096 + t chunks (lane-contiguous).
// TRANS=0: base = W + (j*IN_CAPS + i0)*128 + doff*4 chunks (original layout).
template <int TRANS>
__device__ __forceinline__ void wload(float4 (&w)[4], const float4* __restrict__ base,
                                      int il, int k4) {
    if (TRANS) {
        const float4* p = base + (size_t)il * 4096 + k4 * 1024;
        w[0] = p[0];
        w[1] = p[256];
        w[2] = p[512];
        w[3] = p[768];
    } else {
        const float4* p = base + (size_t)il * 128 + k4;
        w[0] = p[0];
        w[1] = p[4];
        w[2] = p[8];
        w[3] = p[12];
    }
}

// One k-quarter of compute. x read via WAVE-UNIFORM address -> scalar loads;
// each v_fma gets one SGPR operand (x component) + VGPR w + VGPR acc.
template <bool ACCUM>
__device__ __forceinline__ void qcomp(const float4 (&w)[4],
                                      const float* __restrict__ xi,
                                      int k4, float (*__restrict__ dst)[4])
{
#pragma unroll
    for (int b = 0; b < B_CHUNK; ++b) {
        const float* xb = xi + (size_t)b * (IN_CAPS * DIN) + k4 * 4;
        const float x0 = xb[0], x1 = xb[1], x2 = xb[2], x3 = xb[3];
#pragma unroll
        for (int r = 0; r < 4; ++r) {
            const float s = w[r].x * x0 + w[r].y * x1 + w[r].z * x2 + w[r].w * x3;
            if (ACCUM) dst[b][r] += s;
            else       dst[b][r] = s;
        }
    }
}

// PHASE 0: c = 1/32 uniform (softmax of zeros), plain sum.
// PHASE 1: logits = hat . vsum, softmax over j, weighted sum.
template <int PHASE, int ATOMIC, int TRANS>
__launch_bounds__(256, 2)
__global__ void caps_pass(const float* __restrict__ x,
                          const float* __restrict__ Wp,   // W (TRANS=0) or Wt (TRANS=1)
                          const float* __restrict__ vsum,
                          float* __restrict__ P)
{
    __shared__ float c_s[PHASE ? 2 : 1][B_CHUNK][NC];       // 1 KB (phase 1)

    const int t    = threadIdx.x;           // 256 threads
    const int j    = t >> 3;                // 0..31 output capsule
    const int dq   = t & 7;                 // d-quad 0..7
    const int doff = dq * 4;
    const int jd0  = j * DC + doff;

    // XCD-clustered swizzle (round-robin XCD = linear_id % 8):
    // all 16 bg-siblings of one ig occupy consecutive slots on ONE XCD.
    const int r   = blockIdx.x;             // 0..2047
    const int xcd = r & 7;
    const int s   = r >> 3;                 // 0..255
    const int bg  = s & 15;
    const int ig  = (s >> 4) * 8 + xcd;     // 0..127
    const int b0  = bg * B_CHUNK;
    const int i0  = ig * I_CHUNK;

    // W base for this thread
    const float4* base = TRANS
        ? (const float4*)Wp + (size_t)i0 * 4096 + t
        : (const float4*)Wp + ((size_t)j * IN_CAPS + i0) * 128 + doff * 4;

    float4 wE[4], wO[4];
    wload<TRANS>(wE, base, 0, 0);           // prologue: quarter (il=0, k4=0)

    float acc[B_CHUNK][4];
#pragma unroll
    for (int b = 0; b < B_CHUNK; ++b)
#pragma unroll
        for (int dd = 0; dd < 4; ++dd) acc[b][dd] = 0.f;

    float h[B_CHUNK][4];   // phase-1 hat fragments (registers); dead in phase 0
    int buf = 0;

#pragma unroll 1
    for (int il = 0; il < I_CHUNK; ++il) {
        // wave-uniform x row base for this il (scalar loads inside qcomp)
        const float* xi = x + ((size_t)b0 * IN_CAPS + (i0 + il)) * DIN;
        float (*dst)[4] = PHASE ? h : acc;

        // 4 k-quarters, wE/wO ping-pong; next quarter's load issued before the
        // current quarter's compute.
        wload<TRANS>(wO, base, il, 1);
        if (PHASE == 0) qcomp<true >(wE, xi, 0, acc);
        else            qcomp<false>(wE, xi, 0, h);
        wload<TRANS>(wE, base, il, 2);
        qcomp<true>(wO, xi, 1, dst);
        wload<TRANS>(wO, base, il, 3);
        qcomp<true>(wE, xi, 2, dst);
        if (il + 1 < I_CHUNK) wload<TRANS>(wE, base, il + 1, 0);
        qcomp<true>(wO, xi, 3, dst);

        if (PHASE == 1) {
            // logits: lp[b] = hat[b] . vsum[b] over this thread's 4 d's (vsum
            // from global: coalesced, L2-resident), then reduce over the 8
            // dq-threads sharing j.
            float lp[B_CHUNK];
#pragma unroll
            for (int b = 0; b < B_CHUNK; ++b) {
                const float4 vv =
                    *(const float4*)&vsum[(size_t)(b0 + b) * JD + jd0];
                lp[b] = h[b][0]*vv.x + h[b][1]*vv.y + h[b][2]*vv.z + h[b][3]*vv.w;
                lp[b] += __shfl_xor(lp[b], 1, 8);
                lp[b] += __shfl_xor(lp[b], 2, 8);
                lp[b] += __shfl_xor(lp[b], 4, 8);
            }
            if (dq == 0) {
#pragma unroll
                for (int b = 0; b < B_CHUNK; ++b) c_s[buf][b][j] = lp[b];
            }
            LDS_BARRIER();

            // softmax over j: threads t<128 cover 4 b x 32 j; width-32
            // butterflies per row.
            if (t < 128) {
                const int tb = t >> 5, tj = t & 31;
                const float l = c_s[buf][tb][tj];
                float m = l;
                m = fmaxf(m, __shfl_xor(m, 1, 32));
                m = fmaxf(m, __shfl_xor(m, 2, 32));
                m = fmaxf(m, __shfl_xor(m, 4, 32));
                m = fmaxf(m, __shfl_xor(m, 8, 32));
                m = fmaxf(m, __shfl_xor(m, 16, 32));
                const float e = __expf(l - m);
                float ss = e;
                ss += __shfl_xor(ss, 1, 32);
                ss += __shfl_xor(ss, 2, 32);
                ss += __shfl_xor(ss, 4, 32);
                ss += __shfl_xor(ss, 8, 32);
                ss += __shfl_xor(ss, 16, 32);
                c_s[buf][tb][tj] = e / ss;
            }
            LDS_BARRIER();

            // weighted accumulate from register-held hat
#pragma unroll
            for (int b = 0; b < B_CHUNK; ++b) {
                const float c = c_s[buf][b][j];    // broadcast read
                acc[b][0] += c * h[b][0];
                acc[b][1] += c * h[b][1];
                acc[b][2] += c * h[b][2];
                acc[b][3] += c * h[b][3];
            }
            buf ^= 1;   // next il writes the other c_s buffer: no WAR barrier needed
        }
    }

    const float scale = (PHASE == 0) ? (1.f / NC) : 1.f;
    if (ATOMIC) {
#pragma unroll
        for (int b = 0; b < B_CHUNK; ++b) {
            float* dstp = &P[(size_t)(b0 + b) * JD + jd0];
            atomicAdd(dstp + 0, acc[b][0] * scale);
            atomicAdd(dstp + 1, acc[b][1] * scale);
            atomicAdd(dstp + 2, acc[b][2] * scale);
            atomicAdd(dstp + 3, acc[b][3] * scale);
        }
    } else {
        // private partial: P[ig][b_global][jd]; b-split blocks write disjoint
        // b-rows of the same P[ig] slice -> P size unchanged vs B_CHUNK=8.
        float* dstp = P + ((size_t)ig * B_TOT + b0) * JD + jd0;
#pragma unroll
        for (int b = 0; b < B_CHUNK; ++b) {
            *(float4*)(dstp + (size_t)b * JD) =
                make_float4(acc[b][0] * scale, acc[b][1] * scale,
                            acc[b][2] * scale, acc[b][3] * scale);
        }
    }
}

// Sum nparts partials, squash over Dc=32, write per mode.
// Grid 256 blocks x 256 thr: block owns 64 float4-idx; thread sums an ig-slice
// (ig = slice, slice+4, ...), LDS-combine 4 slices, wave 0 squashes + stores.
// mode 0: VSUM = v ; 1: VSUM += v ; 2: OUT = v
__global__ __launch_bounds__(256) void reduce_squash(
    const float* __restrict__ Pf, int nparts,
    float* __restrict__ VSUMf, float* __restrict__ OUTf, int mode)
{
    __shared__ float4 sl[4][64];             // 4 KB
    const float4* P4 = (const float4*)Pf;
    const int t = threadIdx.x, i64 = t & 63, slice = t >> 6;
    const int idx = blockIdx.x * 64 + i64;   // 0..16383
    float4 v = make_float4(0.f, 0.f, 0.f, 0.f);
    for (int ig = slice; ig < nparts; ig += 4) {
        const float4 p = P4[(size_t)ig * (B_TOT * JD / 4) + idx];
        v.x += p.x; v.y += p.y; v.z += p.z; v.w += p.w;
    }
    sl[slice][i64] = v;
    __syncthreads();
    if (t < 64) {
        const float4 a = sl[0][t], b = sl[1][t], c = sl[2][t], d = sl[3][t];
        v.x = a.x + b.x + c.x + d.x;
        v.y = a.y + b.y + c.y + d.y;
        v.z = a.z + b.z + c.z + d.z;
        v.w = a.w + b.w + c.w + d.w;
        float s2 = v.x*v.x + v.y*v.y + v.z*v.z + v.w*v.w;
        s2 += __shfl_xor(s2, 1, 8);
        s2 += __shfl_xor(s2, 2, 8);
        s2 += __shfl_xor(s2, 4, 8);
        const float sc = s2 / (1.f + s2) * rsqrtf(s2 + EPS_SQ);
        const int gidx = blockIdx.x * 64 + t;
        float4 o = make_float4(v.x * sc, v.y * sc, v.z * sc, v.w * sc);
        float4* VSUM = (float4*)VSUMf;
        float4* OUT  = (float4*)OUTf;
        if (mode == 0) {
            VSUM[gidx] = o;
        } else if (mode == 1) {
            float4 u = VSUM[gidx];
            u.x += o.x; u.y += o.y; u.z += o.z; u.w += o.w;
            VSUM[gidx] = u;
        } else {
            OUT[gidx] = o;
        }
    }
}

extern "C" void kernel_launch(void* const* d_in, const int* in_sizes, int n_in,
                              void* d_out, int out_size, void* d_ws, size_t ws_size,
                              hipStream_t stream)
{
    const float* x = (const float*)d_in[0];   // [64, 2048, 16]
    const float* W = (const float*)d_in[1];   // [32, 2048, 32, 16]
    float* out = (float*)d_out;               // [64, 32, 32]

    const dim3 grid(N_IG * N_BG);             // 2048 blocks (XCD-swizzled in-kernel)
    const dim3 blk(256);
    const dim3 rgrid(B_TOT * JD / 4 / 64);    // 256 blocks

    const size_t P_elems  = (size_t)N_IG * B_TOT * JD;              // 33.6 MB
    const size_t vs_elems = (size_t)B_TOT * JD;                     // 256 KB
    const size_t need_p   = (P_elems + vs_elems) * sizeof(float);
    const size_t need_t   = (WT_CHUNKS * 4 + P_elems + vs_elems) * sizeof(float);

    if (ws_size >= need_t) {
        // transposed-W path: lane-contiguous W loads (8 lines/wave-instr)
        float* Wt   = (float*)d_ws;
        float* P    = Wt + WT_CHUNKS * 4;
        float* VSUM = P + P_elems;
        transpose_W<<<dim3(IN_CAPS), blk, 0, stream>>>(W, Wt);
        caps_pass<0, 0, 1><<<grid, blk, 0, stream>>>(x, Wt, nullptr, P);
        reduce_squash<<<rgrid, blk, 0, stream>>>(P, N_IG, VSUM, out, 0);
        caps_pass<1, 0, 1><<<grid, blk, 0, stream>>>(x, Wt, VSUM, P);
        reduce_squash<<<rgrid, blk, 0, stream>>>(P, N_IG, VSUM, out, 1);
        caps_pass<1, 0, 1><<<grid, blk, 0, stream>>>(x, Wt, VSUM, P);
        reduce_squash<<<rgrid, blk, 0, stream>>>(P, N_IG, VSUM, out, 2);
    } else if (ws_size >= need_p) {
        // original-W path
        float* P    = (float*)d_ws;
        float* VSUM = P + P_elems;
        caps_pass<0, 0, 0><<<grid, blk, 0, stream>>>(x, W, nullptr, P);
        reduce_squash<<<rgrid, blk, 0, stream>>>(P, N_IG, VSUM, out, 0);
        caps_pass<1, 0, 0><<<grid, blk, 0, stream>>>(x, W, VSUM, P);
        reduce_squash<<<rgrid, blk, 0, stream>>>(P, N_IG, VSUM, out, 1);
        caps_pass<1, 0, 0><<<grid, blk, 0, stream>>>(x, W, VSUM, P);
        reduce_squash<<<rgrid, blk, 0, stream>>>(P, N_IG, VSUM, out, 2);
    } else {
        // atomic fallback
        float* S    = (float*)d_ws;
        float* VSUM = S + vs_elems;
        const size_t sbytes = vs_elems * sizeof(float);
        hipMemsetAsync(S, 0, sbytes, stream);
        caps_pass<0, 1, 0><<<grid, blk, 0, stream>>>(x, W, nullptr, S);
        reduce_squash<<<rgrid, blk, 0, stream>>>(S, 1, VSUM, out, 0);
        hipMemsetAsync(S, 0, sbytes, stream);
        caps_pass<1, 1, 0><<<grid, blk, 0, stream>>>(x, W, VSUM, S);
        reduce_squash<<<rgrid, blk, 0, stream>>>(S, 1, VSUM, out, 1);
        hipMemsetAsync(S, 0, sbytes, stream);
        caps_pass<1, 1, 0><<<grid, blk, 0, stream>>>(x, W, VSUM, S);
        reduce_squash<<<rgrid, blk, 0, stream>>>(S, 1, VSUM, out, 2);
    }
}